// Round 1
// baseline (727.403 us; speedup 1.0000x reference)
//
#include <hip/hip_runtime.h>

#define S_LEN 2048
#define D_DIM 1024
#define NH 16
#define HD 64

typedef __attribute__((ext_vector_type(8))) short bf16x8;
typedef __attribute__((ext_vector_type(4))) float f32x4;

#define MFMA(a, b, c) __builtin_amdgcn_mfma_f32_16x16x32_bf16((a), (b), (c), 0, 0, 0)

__device__ __forceinline__ unsigned short f2bf(float x) {
    unsigned int u = __float_as_uint(x);
    u = (u + 0x7FFFu + ((u >> 16) & 1u)) >> 16;   // round-to-nearest-even
    return (unsigned short)u;
}
__device__ __forceinline__ float bf2f(unsigned short b) {
    return __uint_as_float(((unsigned int)b) << 16);
}

// ---------------------------------------------------------------------------
// prep_x: split GLO/LOC fp32 -> bf16 hi/lo pairs.  idx in [0, 2*2048*1024)
// ---------------------------------------------------------------------------
__global__ __launch_bounds__(256) void prep_x(const float* __restrict__ GLO,
                                              const float* __restrict__ LOC,
                                              unsigned short* __restrict__ Xh,
                                              unsigned short* __restrict__ Xl) {
    int idx = blockIdx.x * 256 + threadIdx.x;          // 0 .. 4,194,303
    const float* src = (idx & (1 << 21)) ? LOC : GLO;  // 2^21 = 2048*1024
    float x = src[idx & ((1 << 21) - 1)];
    unsigned short h = f2bf(x);
    Xh[idx] = h;
    Xl[idx] = f2bf(x - bf2f(h));
}

// ---------------------------------------------------------------------------
// prep_w: build transposed weights.
//   sec 0: Wq * 0.125 -> split hi/lo, transposed [h][e][d]
//   sec 1: Wk         -> split hi/lo, transposed [h][e][d]
//   sec 2: Wv         -> bf16, transposed [h][e][d]
//   sec 3: Wo         -> bf16, transposed [n][k]
// ---------------------------------------------------------------------------
__global__ __launch_bounds__(256) void prep_w(const float* __restrict__ Wq,
                                              const float* __restrict__ Wk,
                                              const float* __restrict__ Wv,
                                              const float* __restrict__ Wo,
                                              unsigned short* __restrict__ Wqh,
                                              unsigned short* __restrict__ Wql,
                                              unsigned short* __restrict__ Wkh,
                                              unsigned short* __restrict__ Wkl,
                                              unsigned short* __restrict__ Wvt,
                                              unsigned short* __restrict__ Wot) {
    int idx = blockIdx.x * 256 + threadIdx.x;  // 0 .. 4M
    int sec = idx >> 20;
    int i = idx & 0xFFFFF;  // 1M per section
    if (sec < 3) {
        int h = i >> 16;
        int e = (i >> 10) & 63;
        int d = i & 1023;
        float wv = ((sec == 0) ? Wq : (sec == 1) ? Wk : Wv)[h * 65536 + d * 64 + e];
        if (sec == 0) {
            wv *= 0.125f;  // fold 1/sqrt(HD), exact
            unsigned short hi = f2bf(wv);
            Wqh[i] = hi;
            Wql[i] = f2bf(wv - bf2f(hi));
        } else if (sec == 1) {
            unsigned short hi = f2bf(wv);
            Wkh[i] = hi;
            Wkl[i] = f2bf(wv - bf2f(hi));
        } else {
            Wvt[i] = f2bf(wv);
        }
    } else {
        int n = i >> 10, k = i & 1023;
        Wot[i] = f2bf(Wo[k * 1024 + n]);
    }
}

// ---------------------------------------------------------------------------
// proj_qk: D = X @ W with split-bf16 3-pass (XhWh + XhWl + XlWh), fp32 acc,
// output stored as hi/lo bf16 at [src][head][s][e].
// grid: src(2) x head(16) x sblk(32) = 1024 blocks, 256 threads (4 waves)
// ---------------------------------------------------------------------------
__global__ __launch_bounds__(256) void proj_qk(const unsigned short* __restrict__ Xh,
                                               const unsigned short* __restrict__ Xl,
                                               const unsigned short* __restrict__ Bh_,
                                               const unsigned short* __restrict__ Bl_,
                                               unsigned short* __restrict__ Dh,
                                               unsigned short* __restrict__ Dl) {
    const int bid = blockIdx.x;
    const int sblk = bid & 31;
    const int head = (bid >> 5) & 15;
    const int src = bid >> 9;
    const int lane = threadIdx.x & 63;
    const int w = threadIdx.x >> 6;
    const int l15 = lane & 15, quad = lane >> 4;

    const size_t arow = (size_t)src * S_LEN * D_DIM + (size_t)(sblk * 64 + w * 16 + l15) * D_DIM + quad * 8;
    const unsigned short* Ah = Xh + arow;
    const unsigned short* Al = Xl + arow;
    const unsigned short* Bh = Bh_ + head * (HD * D_DIM) + l15 * D_DIM + quad * 8;
    const unsigned short* Bl = Bl_ + head * (HD * D_DIM) + l15 * D_DIM + quad * 8;

    f32x4 acc[4] = {};
    for (int kk = 0; kk < D_DIM; kk += 32) {
        bf16x8 ah = *(const bf16x8*)(Ah + kk);
        bf16x8 al8 = *(const bf16x8*)(Al + kk);
#pragma unroll
        for (int nt = 0; nt < 4; ++nt) {
            bf16x8 bh = *(const bf16x8*)(Bh + nt * 16384 + kk);
            bf16x8 bl = *(const bf16x8*)(Bl + nt * 16384 + kk);
            f32x4 a = acc[nt];
            a = MFMA(ah, bh, a);
            a = MFMA(ah, bl, a);
            a = MFMA(al8, bh, a);
            acc[nt] = a;
        }
    }
    const size_t obase = (size_t)(src * NH + head) * S_LEN * HD;
    const int s_base = sblk * 64 + w * 16 + quad * 4;
#pragma unroll
    for (int nt = 0; nt < 4; ++nt)
#pragma unroll
        for (int r = 0; r < 4; ++r) {
            size_t a = obase + (size_t)(s_base + r) * HD + nt * 16 + l15;
            float v = acc[nt][r];
            unsigned short hi = f2bf(v);
            Dh[a] = hi;
            Dl[a] = f2bf(v - bf2f(hi));
        }
}

// ---------------------------------------------------------------------------
// proj_v: V = X @ Wv (single-pass bf16), stored TRANSPOSED: Vt[src][h][e][s]
// ---------------------------------------------------------------------------
__global__ __launch_bounds__(256) void proj_v(const unsigned short* __restrict__ Xh,
                                              const unsigned short* __restrict__ Bv_,
                                              unsigned short* __restrict__ Vt) {
    const int bid = blockIdx.x;
    const int sblk = bid & 31;
    const int head = (bid >> 5) & 15;
    const int src = bid >> 9;
    const int lane = threadIdx.x & 63;
    const int w = threadIdx.x >> 6;
    const int l15 = lane & 15, quad = lane >> 4;

    const unsigned short* Ah =
        Xh + (size_t)src * S_LEN * D_DIM + (size_t)(sblk * 64 + w * 16 + l15) * D_DIM + quad * 8;
    const unsigned short* Bv = Bv_ + head * (HD * D_DIM) + l15 * D_DIM + quad * 8;

    f32x4 acc[4] = {};
    for (int kk = 0; kk < D_DIM; kk += 32) {
        bf16x8 ah = *(const bf16x8*)(Ah + kk);
#pragma unroll
        for (int nt = 0; nt < 4; ++nt) {
            bf16x8 b = *(const bf16x8*)(Bv + nt * 16384 + kk);
            acc[nt] = MFMA(ah, b, acc[nt]);
        }
    }
    const size_t vbase = (size_t)(src * NH + head) * HD;
    const int s_base = sblk * 64 + w * 16 + quad * 4;
#pragma unroll
    for (int nt = 0; nt < 4; ++nt)
#pragma unroll
        for (int r = 0; r < 4; ++r)
            Vt[(vbase + nt * 16 + l15) * S_LEN + s_base + r] = f2bf(acc[nt][r]);
}

// ---------------------------------------------------------------------------
// attn: flash attention per (dir, head).  Block = 128 q-rows (4 waves x 32),
// key chunks of 64.  Scores = (Qh+Ql)(Kh+Kl)^T 3-pass split-bf16.
// P transposed through per-wave LDS (stride 72 = 144B rows, 16B-aligned).
// Output stored with the torch-.view scramble: row q' = h*128 + (q>>4),
// col f = (q&15)*64 + e.
// grid: dir(2) x head(16) x qblk(16) = 512 blocks
// ---------------------------------------------------------------------------
__global__ __launch_bounds__(256) void attn_kernel(const unsigned short* __restrict__ Qh_,
                                                   const unsigned short* __restrict__ Ql_,
                                                   const unsigned short* __restrict__ Kh_,
                                                   const unsigned short* __restrict__ Kl_,
                                                   const unsigned short* __restrict__ Vt_,
                                                   unsigned short* __restrict__ Oatt) {
    __shared__ unsigned short Plds[4 * 2 * 16 * 72];  // 18 KiB
    const int bid = blockIdx.x;
    const int qblk = bid & 15;
    const int head = (bid >> 4) & 15;
    const int dir = bid >> 8;
    const int src_q = dir, src_kv = 1 - dir;

    const int lane = threadIdx.x & 63;
    const int w = threadIdx.x >> 6;
    const int l15 = lane & 15, quad = lane >> 4;
    const int q0 = qblk * 128 + w * 32;

    const unsigned short* Qhp = Qh_ + ((size_t)(src_q * NH + head) * S_LEN + q0) * HD;
    const unsigned short* Qlp = Ql_ + ((size_t)(src_q * NH + head) * S_LEN + q0) * HD;

    bf16x8 qh[2][2], ql[2][2];
#pragma unroll
    for (int mt = 0; mt < 2; ++mt)
#pragma unroll
        for (int c = 0; c < 2; ++c) {
            qh[mt][c] = *(const bf16x8*)(Qhp + (mt * 16 + l15) * HD + c * 32 + quad * 8);
            ql[mt][c] = *(const bf16x8*)(Qlp + (mt * 16 + l15) * HD + c * 32 + quad * 8);
        }

    const unsigned short* Khp = Kh_ + (size_t)(src_kv * NH + head) * S_LEN * HD;
    const unsigned short* Klp = Kl_ + (size_t)(src_kv * NH + head) * S_LEN * HD;
    const unsigned short* Vtp = Vt_ + (size_t)(src_kv * NH + head) * HD * S_LEN;

    f32x4 o[2][4] = {};
    float mi[2][4], li[2][4];
#pragma unroll
    for (int mt = 0; mt < 2; ++mt)
#pragma unroll
        for (int r = 0; r < 4; ++r) {
            mi[mt][r] = -1e30f;
            li[mt][r] = 0.f;
        }

    unsigned short* myP = Plds + w * (2 * 16 * 72);

    for (int k0 = 0; k0 < S_LEN; k0 += 64) {
        f32x4 sa[2][4] = {};
#pragma unroll
        for (int nt = 0; nt < 4; ++nt) {
            const unsigned short* kb = Khp + (size_t)(k0 + nt * 16 + l15) * HD + quad * 8;
            const unsigned short* lb = Klp + (size_t)(k0 + nt * 16 + l15) * HD + quad * 8;
            bf16x8 bh0 = *(const bf16x8*)kb;
            bf16x8 bh1 = *(const bf16x8*)(kb + 32);
            bf16x8 bl0 = *(const bf16x8*)lb;
            bf16x8 bl1 = *(const bf16x8*)(lb + 32);
#pragma unroll
            for (int mt = 0; mt < 2; ++mt) {
                f32x4 a = sa[mt][nt];
                a = MFMA(qh[mt][0], bh0, a);
                a = MFMA(qh[mt][1], bh1, a);
                a = MFMA(qh[mt][0], bl0, a);
                a = MFMA(qh[mt][1], bl1, a);
                a = MFMA(ql[mt][0], bh0, a);
                a = MFMA(ql[mt][1], bh1, a);
                sa[mt][nt] = a;
            }
        }
        // online softmax per m-tile (rows m = quad*4+r live across the 16
        // lanes of this quad-group; reduce with xor-shuffles 1,2,4,8)
#pragma unroll
        for (int mt = 0; mt < 2; ++mt) {
            float tm[4];
#pragma unroll
            for (int r = 0; r < 4; ++r)
                tm[r] = fmaxf(fmaxf(sa[mt][0][r], sa[mt][1][r]), fmaxf(sa[mt][2][r], sa[mt][3][r]));
#pragma unroll
            for (int off = 1; off <= 8; off <<= 1)
#pragma unroll
                for (int r = 0; r < 4; ++r) tm[r] = fmaxf(tm[r], __shfl_xor(tm[r], off, 64));
            float al[4], rs[4];
#pragma unroll
            for (int r = 0; r < 4; ++r) {
                float mn = fmaxf(mi[mt][r], tm[r]);
                al[r] = __expf(mi[mt][r] - mn);
                mi[mt][r] = mn;
                rs[r] = 0.f;
            }
#pragma unroll
            for (int nt = 0; nt < 4; ++nt)
#pragma unroll
                for (int r = 0; r < 4; ++r) {
                    float p = __expf(sa[mt][nt][r] - mi[mt][r]);
                    sa[mt][nt][r] = p;
                    rs[r] += p;
                }
#pragma unroll
            for (int off = 1; off <= 8; off <<= 1)
#pragma unroll
                for (int r = 0; r < 4; ++r) rs[r] += __shfl_xor(rs[r], off, 64);
#pragma unroll
            for (int r = 0; r < 4; ++r) li[mt][r] = li[mt][r] * al[r] + rs[r];
#pragma unroll
            for (int nt = 0; nt < 4; ++nt)
#pragma unroll
                for (int r = 0; r < 4; ++r) o[mt][nt][r] *= al[r];
            unsigned short* pp = myP + mt * (16 * 72);
#pragma unroll
            for (int nt = 0; nt < 4; ++nt)
#pragma unroll
                for (int r = 0; r < 4; ++r)
                    pp[(quad * 4 + r) * 72 + nt * 16 + l15] = f2bf(sa[mt][nt][r]);
        }
        // PV: A-frags from LDS (A-layout), V B-frags from transposed global V
#pragma unroll
        for (int c = 0; c < 2; ++c) {
            bf16x8 af[2];
#pragma unroll
            for (int mt = 0; mt < 2; ++mt)
                af[mt] = *(const bf16x8*)(myP + mt * (16 * 72) + l15 * 72 + c * 32 + quad * 8);
#pragma unroll
            for (int nt = 0; nt < 4; ++nt) {
                bf16x8 vf =
                    *(const bf16x8*)(Vtp + (size_t)(nt * 16 + l15) * S_LEN + k0 + c * 32 + quad * 8);
#pragma unroll
                for (int mt = 0; mt < 2; ++mt) o[mt][nt] = MFMA(af[mt], vf, o[mt][nt]);
            }
        }
    }
    // normalize + store with the raw-.view scramble
#pragma unroll
    for (int mt = 0; mt < 2; ++mt)
#pragma unroll
        for (int nt = 0; nt < 4; ++nt)
#pragma unroll
            for (int r = 0; r < 4; ++r) {
                int q = q0 + mt * 16 + quad * 4 + r;
                int e = nt * 16 + l15;
                int qp = head * 128 + (q >> 4);
                int f = (q & 15) * 64 + e;
                float v = o[mt][nt][r] / li[mt][r];
                Oatt[(size_t)(dir * S_LEN + qp) * D_DIM + f] = f2bf(v);
            }
}

// ---------------------------------------------------------------------------
// oproj: out[dir] = Oatt[dir] @ Wo   (bf16 MFMA, fp32 out)
// grid: dir(2) x sblk(32) x nblk(16) = 1024 blocks
// ---------------------------------------------------------------------------
__global__ __launch_bounds__(256) void oproj(const unsigned short* __restrict__ Oatt,
                                             const unsigned short* __restrict__ Wot,
                                             float* __restrict__ out) {
    const int bid = blockIdx.x;
    const int nblk = bid & 15;
    const int sblk = (bid >> 4) & 31;
    const int dir = bid >> 9;
    const int lane = threadIdx.x & 63;
    const int w = threadIdx.x >> 6;
    const int l15 = lane & 15, quad = lane >> 4;

    const unsigned short* Ap =
        Oatt + (size_t)(dir * S_LEN + sblk * 64 + w * 16 + l15) * D_DIM + quad * 8;
    const unsigned short* Bp = Wot + (size_t)(nblk * 64 + l15) * D_DIM + quad * 8;

    f32x4 acc[4] = {};
    for (int kk = 0; kk < D_DIM; kk += 32) {
        bf16x8 a = *(const bf16x8*)(Ap + kk);
#pragma unroll
        for (int nt = 0; nt < 4; ++nt) {
            bf16x8 b = *(const bf16x8*)(Bp + nt * 16384 + kk);
            acc[nt] = MFMA(a, b, acc[nt]);
        }
    }
    const int row = sblk * 64 + w * 16 + quad * 4;
#pragma unroll
    for (int nt = 0; nt < 4; ++nt)
#pragma unroll
        for (int r = 0; r < 4; ++r)
            out[(size_t)dir * (S_LEN * D_DIM) + (size_t)(row + r) * D_DIM + nblk * 64 + nt * 16 +
                l15] = acc[nt][r];
}

// ---------------------------------------------------------------------------
extern "C" void kernel_launch(void* const* d_in, const int* in_sizes, int n_in, void* d_out,
                              int out_size, void* d_ws, size_t ws_size, hipStream_t stream) {
    const float* GLO = (const float*)d_in[0];
    const float* LOC = (const float*)d_in[1];
    const float* Wq = (const float*)d_in[2];
    const float* Wk = (const float*)d_in[3];
    const float* Wv = (const float*)d_in[4];
    const float* Wo = (const float*)d_in[5];
    float* out = (float*)d_out;

    // workspace layout (ushort element offsets); total 79,691,776 bytes
    unsigned short* ws = (unsigned short*)d_ws;
    unsigned short* Xh = ws + 0;
    unsigned short* Xl = ws + 4194304;
    unsigned short* Wqh = ws + 8388608;
    unsigned short* Wql = ws + 9437184;
    unsigned short* Wkh = ws + 10485760;
    unsigned short* Wkl = ws + 11534336;
    unsigned short* Wvt = ws + 12582912;
    unsigned short* Wot = ws + 13631488;
    unsigned short* Qh = ws + 14680064;
    unsigned short* Ql = ws + 18874368;
    unsigned short* Kh = ws + 23068672;
    unsigned short* Kl = ws + 27262976;
    unsigned short* Vt = ws + 31457280;
    unsigned short* Oatt = ws + 35651584;

    prep_x<<<16384, 256, 0, stream>>>(GLO, LOC, Xh, Xl);
    prep_w<<<16384, 256, 0, stream>>>(Wq, Wk, Wv, Wo, Wqh, Wql, Wkh, Wkl, Wvt, Wot);
    proj_qk<<<1024, 256, 0, stream>>>(Xh, Xl, Wqh, Wql, Qh, Ql);
    proj_qk<<<1024, 256, 0, stream>>>(Xh, Xl, Wkh, Wkl, Kh, Kl);
    proj_v<<<1024, 256, 0, stream>>>(Xh, Wvt, Vt);
    attn_kernel<<<512, 256, 0, stream>>>(Qh, Ql, Kh, Kl, Vt, Oatt);
    oproj<<<1024, 256, 0, stream>>>(Oatt, Wot, out);
}

// Round 2
// 615.257 us; speedup vs baseline: 1.1823x; 1.1823x over previous
//
#include <hip/hip_runtime.h>

#define S_LEN 2048
#define D_DIM 1024
#define NH 16
#define HD 64

typedef __attribute__((ext_vector_type(8))) short bf16x8;
typedef __attribute__((ext_vector_type(4))) float f32x4;

#define MFMA(a, b, c) __builtin_amdgcn_mfma_f32_16x16x32_bf16((a), (b), (c), 0, 0, 0)

__device__ __forceinline__ unsigned short f2bf(float x) {
    unsigned int u = __float_as_uint(x);
    u = (u + 0x7FFFu + ((u >> 16) & 1u)) >> 16;  // round-to-nearest-even
    return (unsigned short)u;
}
__device__ __forceinline__ float bf2f(unsigned short b) {
    return __uint_as_float(((unsigned int)b) << 16);
}
__device__ __forceinline__ void gl_lds16(const void* g, void* l) {
    __builtin_amdgcn_global_load_lds((const __attribute__((address_space(1))) unsigned int*)g,
                                     (__attribute__((address_space(3))) unsigned int*)l, 16, 0, 0);
}

// ---------------------------------------------------------------------------
// prep: fused input split + weight transpose/split.
//   idx < 4M          : X split (GLO rows 0..2047, LOC rows 2048..4095)
//   idx in [4M, 8M)   : weights (4 sections of 1M: Wq*0.125 hi/lo, Wk hi/lo,
//                       Wv, Wo), all stored [n][k]
// ---------------------------------------------------------------------------
__global__ __launch_bounds__(256) void prep(const float* __restrict__ GLO,
                                            const float* __restrict__ LOC,
                                            const float* __restrict__ Wq,
                                            const float* __restrict__ Wk,
                                            const float* __restrict__ Wv,
                                            const float* __restrict__ Wo,
                                            unsigned short* __restrict__ Xh,
                                            unsigned short* __restrict__ Xl,
                                            unsigned short* __restrict__ Wqh,
                                            unsigned short* __restrict__ Wql,
                                            unsigned short* __restrict__ Wkh,
                                            unsigned short* __restrict__ Wkl,
                                            unsigned short* __restrict__ Wvt,
                                            unsigned short* __restrict__ Wot) {
    int idx = blockIdx.x * 256 + threadIdx.x;  // 0 .. 8M-1
    if (idx < (1 << 22)) {
        const float* src = (idx & (1 << 21)) ? LOC : GLO;
        float x = src[idx & ((1 << 21) - 1)];
        unsigned short h = f2bf(x);
        Xh[idx] = h;
        Xl[idx] = f2bf(x - bf2f(h));
    } else {
        idx -= (1 << 22);
        int sec = idx >> 20;
        int i = idx & 0xFFFFF;
        if (sec < 3) {
            int h = i >> 16;
            int e = (i >> 10) & 63;
            int d = i & 1023;
            float wv = ((sec == 0) ? Wq : (sec == 1) ? Wk : Wv)[h * 65536 + d * 64 + e];
            if (sec == 0) {
                wv *= 0.125f;  // fold 1/sqrt(HD), exact
                unsigned short hi = f2bf(wv);
                Wqh[i] = hi;
                Wql[i] = f2bf(wv - bf2f(hi));
            } else if (sec == 1) {
                unsigned short hi = f2bf(wv);
                Wkh[i] = hi;
                Wkl[i] = f2bf(wv - bf2f(hi));
            } else {
                Wvt[i] = f2bf(wv);
            }
        } else {
            int n = i >> 10, k = i & 1023;
            Wot[i] = f2bf(Wo[k * 1024 + n]);
        }
    }
}

// ---------------------------------------------------------------------------
// qkv_proj: one pass over X produces Q (hi/lo), K (hi/lo), V.
//   Q,K layout: [4096 rows][1024 cols], col = head*64 + e
//   V layout (transposed): Vt[col][4096], col = head*64 + e
// grid: src(2) x head(16) x sblk(32, 64 rows) = 1024 blocks, 4 waves x 16 rows
// ---------------------------------------------------------------------------
__global__ __launch_bounds__(256) void qkv_proj(const unsigned short* __restrict__ Xh,
                                                const unsigned short* __restrict__ Xl,
                                                const unsigned short* __restrict__ Wqh,
                                                const unsigned short* __restrict__ Wql,
                                                const unsigned short* __restrict__ Wkh,
                                                const unsigned short* __restrict__ Wkl,
                                                const unsigned short* __restrict__ Wvt,
                                                unsigned short* __restrict__ Qh,
                                                unsigned short* __restrict__ Ql,
                                                unsigned short* __restrict__ Kh,
                                                unsigned short* __restrict__ Kl,
                                                unsigned short* __restrict__ Vt) {
    const int bid = blockIdx.x;
    const int sblk = bid & 31;
    const int head = (bid >> 5) & 15;
    const int src = bid >> 9;
    const int lane = threadIdx.x & 63;
    const int w = threadIdx.x >> 6;
    const int l15 = lane & 15, quad = lane >> 4;

    const int arow = src * S_LEN + sblk * 64 + w * 16 + l15;
    const unsigned short* Ah = Xh + (size_t)arow * D_DIM + quad * 8;
    const unsigned short* Al = Xl + (size_t)arow * D_DIM + quad * 8;
    const size_t boff = (size_t)(head * 64 + l15) * D_DIM + quad * 8;
    const unsigned short* Bqh = Wqh + boff;
    const unsigned short* Bql = Wql + boff;
    const unsigned short* Bkh = Wkh + boff;
    const unsigned short* Bkl = Wkl + boff;
    const unsigned short* Bv = Wvt + boff;

    f32x4 aq[4] = {}, ak[4] = {}, av[4] = {};
#pragma unroll 2
    for (int kk = 0; kk < D_DIM; kk += 32) {
        bf16x8 ah = *(const bf16x8*)(Ah + kk);
        bf16x8 al8 = *(const bf16x8*)(Al + kk);
#pragma unroll
        for (int nt = 0; nt < 4; ++nt) {
            const int o = nt * 16384 + kk;
            bf16x8 bqh = *(const bf16x8*)(Bqh + o);
            bf16x8 bql = *(const bf16x8*)(Bql + o);
            bf16x8 bkh = *(const bf16x8*)(Bkh + o);
            bf16x8 bkl = *(const bf16x8*)(Bkl + o);
            bf16x8 bv = *(const bf16x8*)(Bv + o);
            f32x4 a = aq[nt];
            a = MFMA(ah, bqh, a);
            a = MFMA(ah, bql, a);
            a = MFMA(al8, bqh, a);
            aq[nt] = a;
            f32x4 b = ak[nt];
            b = MFMA(ah, bkh, b);
            b = MFMA(ah, bkl, b);
            b = MFMA(al8, bkh, b);
            ak[nt] = b;
            av[nt] = MFMA(ah, bv, av[nt]);
        }
    }
    const int s_base = src * S_LEN + sblk * 64 + w * 16 + quad * 4;
#pragma unroll
    for (int nt = 0; nt < 4; ++nt) {
        const int col = head * 64 + nt * 16 + l15;
#pragma unroll
        for (int r = 0; r < 4; ++r) {
            size_t a = (size_t)(s_base + r) * D_DIM + col;
            float vq = aq[nt][r];
            unsigned short hq = f2bf(vq);
            Qh[a] = hq;
            Ql[a] = f2bf(vq - bf2f(hq));
            float vk = ak[nt][r];
            unsigned short hk = f2bf(vk);
            Kh[a] = hk;
            Kl[a] = f2bf(vk - bf2f(hk));
            Vt[(size_t)col * (2 * S_LEN) + s_base + r] = f2bf(av[nt][r]);
        }
    }
}

// ---------------------------------------------------------------------------
// attn: flash attention per (dir, head).  Block = 64 q-rows (4 waves x 16),
// key chunks of 64 staged into LDS via global_load_lds (Khi/Klo/V, 24 KB),
// XOR-swizzled on the global-gather side to avoid stride-128B bank conflicts.
// P transposed through per-wave LDS (stride 72, 16B-aligned).
// Output stored with the torch-.view scramble: row q' = h*128 + (q>>4),
// col f = (q&15)*64 + e.
// grid: dir(2) x head(16) x qblk(32) = 1024 blocks
// ---------------------------------------------------------------------------
__global__ __launch_bounds__(256) void attn_kernel(const unsigned short* __restrict__ Qh_,
                                                   const unsigned short* __restrict__ Ql_,
                                                   const unsigned short* __restrict__ Kh_,
                                                   const unsigned short* __restrict__ Kl_,
                                                   const unsigned short* __restrict__ Vt_,
                                                   unsigned short* __restrict__ Oatt) {
    __shared__ unsigned short lds[16896];  // Khi[0,4096) Klo[4096,8192) V[8192,12288) P[12288,16896)
    const int bid = blockIdx.x;
    const int qblk = bid & 31;
    const int head = (bid >> 5) & 15;
    const int dir = bid >> 9;
    const int src_q = dir, src_kv = 1 - dir;

    const int tid = threadIdx.x;
    const int lane = tid & 63;
    const int w = tid >> 6;
    const int l15 = lane & 15, quad = lane >> 4;
    const int q0 = qblk * 64 + w * 16;

    // Q fragments (A-layout): A[m=l15][k=c*32+quad*8+j]
    const size_t qrow = (size_t)(src_q * S_LEN + q0 + l15) * D_DIM + head * 64 + quad * 8;
    bf16x8 qh[2], ql[2];
#pragma unroll
    for (int c = 0; c < 2; ++c) {
        qh[c] = *(const bf16x8*)(Qh_ + qrow + c * 32);
        ql[c] = *(const bf16x8*)(Ql_ + qrow + c * 32);
    }

    f32x4 o[4] = {};
    float mi[4], li[4];
#pragma unroll
    for (int r = 0; r < 4; ++r) {
        mi[r] = -1e30f;
        li[r] = 0.f;
    }

    unsigned short* Pw = lds + 12288 + w * 1152;

    for (int k0 = 0; k0 < S_LEN; k0 += 64) {
        __syncthreads();
        {
            const unsigned short* KhB = Kh_ + (size_t)(src_kv * S_LEN + k0) * D_DIM + head * 64;
            const unsigned short* KlB = Kl_ + (size_t)(src_kv * S_LEN + k0) * D_DIM + head * 64;
            const unsigned short* VB = Vt_ + (size_t)(head * 64) * (2 * S_LEN) + src_kv * S_LEN + k0;
#pragma unroll
            for (int j = 0; j < 2; ++j) {
                int i = j * 256 + tid;  // segment 0..511
                int row = i >> 3, c16 = i & 7;
                int sc = c16 ^ (row & 7);  // swizzle on global side
                gl_lds16(KhB + (size_t)row * D_DIM + sc * 8, &lds[i * 8]);
                gl_lds16(KlB + (size_t)row * D_DIM + sc * 8, &lds[4096 + i * 8]);
                gl_lds16(VB + (size_t)row * (2 * S_LEN) + sc * 8, &lds[8192 + i * 8]);
            }
        }
        __syncthreads();

        // QK^T (split-bf16 3-pass)
        f32x4 sa[4] = {};
#pragma unroll
        for (int nt = 0; nt < 4; ++nt) {
            const int row = nt * 16 + l15;
            const int s0 = (quad ^ (row & 7)) * 8;
            const int s1 = ((4 + quad) ^ (row & 7)) * 8;
            bf16x8 bh0 = *(const bf16x8*)&lds[row * 64 + s0];
            bf16x8 bh1 = *(const bf16x8*)&lds[row * 64 + s1];
            bf16x8 bl0 = *(const bf16x8*)&lds[4096 + row * 64 + s0];
            bf16x8 bl1 = *(const bf16x8*)&lds[4096 + row * 64 + s1];
            f32x4 a = sa[nt];
            a = MFMA(qh[0], bh0, a);
            a = MFMA(qh[1], bh1, a);
            a = MFMA(qh[0], bl0, a);
            a = MFMA(qh[1], bl1, a);
            a = MFMA(ql[0], bh0, a);
            a = MFMA(ql[1], bh1, a);
            sa[nt] = a;
        }

        // online softmax (rows quad*4+r; reduce across l15 within quad)
        float tm[4];
#pragma unroll
        for (int r = 0; r < 4; ++r)
            tm[r] = fmaxf(fmaxf(sa[0][r], sa[1][r]), fmaxf(sa[2][r], sa[3][r]));
#pragma unroll
        for (int off = 1; off <= 8; off <<= 1)
#pragma unroll
            for (int r = 0; r < 4; ++r) tm[r] = fmaxf(tm[r], __shfl_xor(tm[r], off, 64));
        float al[4], rs[4];
#pragma unroll
        for (int r = 0; r < 4; ++r) {
            float mn = fmaxf(mi[r], tm[r]);
            al[r] = __expf(mi[r] - mn);
            mi[r] = mn;
            rs[r] = 0.f;
        }
#pragma unroll
        for (int nt = 0; nt < 4; ++nt)
#pragma unroll
            for (int r = 0; r < 4; ++r) {
                float p = __expf(sa[nt][r] - mi[r]);
                sa[nt][r] = p;
                rs[r] += p;
            }
#pragma unroll
        for (int off = 1; off <= 8; off <<= 1)
#pragma unroll
            for (int r = 0; r < 4; ++r) rs[r] += __shfl_xor(rs[r], off, 64);
#pragma unroll
        for (int r = 0; r < 4; ++r) li[r] = li[r] * al[r] + rs[r];
#pragma unroll
        for (int nt = 0; nt < 4; ++nt)
#pragma unroll
            for (int r = 0; r < 4; ++r) o[nt][r] *= al[r];
#pragma unroll
        for (int nt = 0; nt < 4; ++nt)
#pragma unroll
            for (int r = 0; r < 4; ++r)
                Pw[(quad * 4 + r) * 72 + nt * 16 + l15] = f2bf(sa[nt][r]);

        // PV: A-frags from P LDS, V B-frags from staged LDS
#pragma unroll
        for (int c = 0; c < 2; ++c) {
            bf16x8 af = *(const bf16x8*)(Pw + l15 * 72 + c * 32 + quad * 8);
#pragma unroll
            for (int nt = 0; nt < 4; ++nt) {
                const int row = nt * 16 + l15;
                const int sl = ((c * 4 + quad) ^ (row & 7)) * 8;
                bf16x8 vf = *(const bf16x8*)&lds[8192 + row * 64 + sl];
                o[nt] = MFMA(af, vf, o[nt]);
            }
        }
    }
    // normalize + store with the raw-.view scramble
#pragma unroll
    for (int nt = 0; nt < 4; ++nt)
#pragma unroll
        for (int r = 0; r < 4; ++r) {
            int q = q0 + quad * 4 + r;
            int e = nt * 16 + l15;
            int qp = head * 128 + (q >> 4);
            int f = (q & 15) * 64 + e;
            Oatt[(size_t)(dir * S_LEN + qp) * D_DIM + f] = f2bf(o[nt][r] / li[r]);
        }
}

// ---------------------------------------------------------------------------
// oproj: out[dir] = Oatt[dir] @ Wo   (bf16 MFMA, fp32 out)
// grid: dir(2) x sblk(32) x nblk(16) = 1024 blocks
// ---------------------------------------------------------------------------
__global__ __launch_bounds__(256) void oproj(const unsigned short* __restrict__ Oatt,
                                             const unsigned short* __restrict__ Wot,
                                             float* __restrict__ out) {
    const int bid = blockIdx.x;
    const int nblk = bid & 15;
    const int sblk = (bid >> 4) & 31;
    const int dir = bid >> 9;
    const int lane = threadIdx.x & 63;
    const int w = threadIdx.x >> 6;
    const int l15 = lane & 15, quad = lane >> 4;

    const unsigned short* Ap =
        Oatt + (size_t)(dir * S_LEN + sblk * 64 + w * 16 + l15) * D_DIM + quad * 8;
    const unsigned short* Bp = Wot + (size_t)(nblk * 64 + l15) * D_DIM + quad * 8;

    f32x4 acc[4] = {};
#pragma unroll 2
    for (int kk = 0; kk < D_DIM; kk += 32) {
        bf16x8 a = *(const bf16x8*)(Ap + kk);
#pragma unroll
        for (int nt = 0; nt < 4; ++nt) {
            bf16x8 b = *(const bf16x8*)(Bp + nt * 16384 + kk);
            acc[nt] = MFMA(a, b, acc[nt]);
        }
    }
    const int row = sblk * 64 + w * 16 + quad * 4;
#pragma unroll
    for (int nt = 0; nt < 4; ++nt)
#pragma unroll
        for (int r = 0; r < 4; ++r)
            out[(size_t)dir * (S_LEN * D_DIM) + (size_t)(row + r) * D_DIM + nblk * 64 + nt * 16 +
                l15] = acc[nt][r];
}

// ---------------------------------------------------------------------------
extern "C" void kernel_launch(void* const* d_in, const int* in_sizes, int n_in, void* d_out,
                              int out_size, void* d_ws, size_t ws_size, hipStream_t stream) {
    const float* GLO = (const float*)d_in[0];
    const float* LOC = (const float*)d_in[1];
    const float* Wq = (const float*)d_in[2];
    const float* Wk = (const float*)d_in[3];
    const float* Wv = (const float*)d_in[4];
    const float* Wo = (const float*)d_in[5];
    float* out = (float*)d_out;

    // workspace layout (ushort element offsets); total 79,691,776 bytes
    unsigned short* ws = (unsigned short*)d_ws;
    unsigned short* Xh = ws + 0;
    unsigned short* Xl = ws + 4194304;
    unsigned short* Wqh = ws + 8388608;
    unsigned short* Wql = ws + 9437184;
    unsigned short* Wkh = ws + 10485760;
    unsigned short* Wkl = ws + 11534336;
    unsigned short* Wvt = ws + 12582912;
    unsigned short* Wot = ws + 13631488;
    unsigned short* Qh = ws + 14680064;
    unsigned short* Ql = ws + 18874368;
    unsigned short* Kh = ws + 23068672;
    unsigned short* Kl = ws + 27262976;
    unsigned short* Vt = ws + 31457280;
    unsigned short* Oatt = ws + 35651584;

    prep<<<32768, 256, 0, stream>>>(GLO, LOC, Wq, Wk, Wv, Wo, Xh, Xl, Wqh, Wql, Wkh, Wkl, Wvt, Wot);
    qkv_proj<<<1024, 256, 0, stream>>>(Xh, Xl, Wqh, Wql, Wkh, Wkl, Wvt, Qh, Ql, Kh, Kl, Vt);
    attn_kernel<<<1024, 256, 0, stream>>>(Qh, Ql, Kh, Kl, Vt, Oatt);
    oproj<<<1024, 256, 0, stream>>>(Oatt, Wot, out);
}

// Round 3
// 347.719 us; speedup vs baseline: 2.0919x; 1.7694x over previous
//
#include <hip/hip_runtime.h>

#define S_LEN 2048
#define D_DIM 1024
#define NH 16
#define HD 64

typedef __attribute__((ext_vector_type(8))) short bf16x8;
typedef __attribute__((ext_vector_type(4))) float f32x4;

#define MFMA(a, b, c) __builtin_amdgcn_mfma_f32_16x16x32_bf16((a), (b), (c), 0, 0, 0)

__device__ __forceinline__ unsigned short f2bf(float x) {
    unsigned int u = __float_as_uint(x);
    u = (u + 0x7FFFu + ((u >> 16) & 1u)) >> 16;  // round-to-nearest-even
    return (unsigned short)u;
}
__device__ __forceinline__ float bf2f(unsigned short b) {
    return __uint_as_float(((unsigned int)b) << 16);
}
__device__ __forceinline__ void gl_lds16(const void* g, void* l) {
    __builtin_amdgcn_global_load_lds((const __attribute__((address_space(1))) unsigned int*)g,
                                     (__attribute__((address_space(3))) unsigned int*)l, 16, 0, 0);
}

// Tiled-swizzled layouts (baked by prep, consumed by qkv_proj staging):
//   X  : [mblk=r>>7][kblk=k>>6][row=r&127][g=((k>>3)&7)^(r&7)][k&7]
//   Wqkv: [head][kblk=d>>6][col=e][g=((d>>3)&7)^(e&7)][d&7]
// so a (128x64) A-tile / (64x64) B-tile is one contiguous 16/8 KB chunk and
// global_load_lds is an identity copy; LDS fragment reads are 2-way = free.

// ---------------------------------------------------------------------------
// prep: fused input split + weight transpose/split.
// ---------------------------------------------------------------------------
__global__ __launch_bounds__(256) void prep(const float* __restrict__ GLO,
                                            const float* __restrict__ LOC,
                                            const float* __restrict__ Wq,
                                            const float* __restrict__ Wk,
                                            const float* __restrict__ Wv,
                                            const float* __restrict__ Wo,
                                            unsigned short* __restrict__ Xh,
                                            unsigned short* __restrict__ Xl,
                                            unsigned short* __restrict__ Wqh,
                                            unsigned short* __restrict__ Wql,
                                            unsigned short* __restrict__ Wkh,
                                            unsigned short* __restrict__ Wkl,
                                            unsigned short* __restrict__ Wvt,
                                            unsigned short* __restrict__ Wot) {
    int idx = blockIdx.x * 256 + threadIdx.x;  // 0 .. 8M-1
    if (idx < (1 << 22)) {
        const float* src = (idx & (1 << 21)) ? LOC : GLO;
        float x = src[idx & ((1 << 21) - 1)];
        int r = idx >> 10;   // 0..4095 (src*2048 + s)
        int k = idx & 1023;
        size_t t = (size_t)(r >> 7) * 131072 + (size_t)(k >> 6) * 8192 + (r & 127) * 64 +
                   ((((k >> 3) & 7) ^ (r & 7)) * 8) + (k & 7);
        unsigned short h = f2bf(x);
        Xh[t] = h;
        Xl[t] = f2bf(x - bf2f(h));
    } else {
        idx -= (1 << 22);
        int sec = idx >> 20;
        int i = idx & 0xFFFFF;
        if (sec < 3) {
            int h = i >> 16;
            int e = (i >> 10) & 63;
            int d = i & 1023;
            float wv = ((sec == 0) ? Wq : (sec == 1) ? Wk : Wv)[h * 65536 + d * 64 + e];
            size_t t = (size_t)h * 65536 + (size_t)(d >> 6) * 4096 + e * 64 +
                       ((((d >> 3) & 7) ^ (e & 7)) * 8) + (d & 7);
            if (sec == 0) {
                wv *= 0.125f;  // fold 1/sqrt(HD), exact
                unsigned short hi = f2bf(wv);
                Wqh[t] = hi;
                Wql[t] = f2bf(wv - bf2f(hi));
            } else if (sec == 1) {
                unsigned short hi = f2bf(wv);
                Wkh[t] = hi;
                Wkl[t] = f2bf(wv - bf2f(hi));
            } else {
                Wvt[t] = f2bf(wv);
            }
        } else {
            int n = i >> 10, k = i & 1023;
            Wot[i] = f2bf(Wo[k * 1024 + n]);  // [n][k] row-major for oproj
        }
    }
}

// ---------------------------------------------------------------------------
// qkv_proj: staged-LDS GEMM. Block = 128 rows x 1 head (64 cols), 4 waves x
// 32 rows, BK=64, 72 KB LDS single-buffered.  7 MFMA passes share staged A/B.
//   Q,K out: row-major [4096][1024], col = head*64+e, hi/lo split
//   V  out: transposed Vt[col][4096]
// grid: mblk(32) x head(16) = 512 blocks
// ---------------------------------------------------------------------------
__global__ __launch_bounds__(256) void qkv_proj(const unsigned short* __restrict__ Xh,
                                                const unsigned short* __restrict__ Xl,
                                                const unsigned short* __restrict__ Wqh,
                                                const unsigned short* __restrict__ Wql,
                                                const unsigned short* __restrict__ Wkh,
                                                const unsigned short* __restrict__ Wkl,
                                                const unsigned short* __restrict__ Wvt,
                                                unsigned short* __restrict__ Qh,
                                                unsigned short* __restrict__ Ql,
                                                unsigned short* __restrict__ Kh,
                                                unsigned short* __restrict__ Kl,
                                                unsigned short* __restrict__ Vt) {
    // LDS element offsets: Xh 0, Xl 8192, Wqh 16384, Wql 20480, Wkh 24576,
    // Wkl 28672, Wv 32768  (total 36864 elem = 72 KB)
    __shared__ unsigned short lds[36864];
    const int bid = blockIdx.x;
    const int mblk = bid & 31;
    const int head = bid >> 5;
    const int tid = threadIdx.x;
    const int lane = tid & 63;
    const int w = tid >> 6;
    const int l15 = lane & 15, quad = lane >> 4;

    f32x4 aq[2][4] = {}, ak[2][4] = {}, av[2][4] = {};

    const size_t abase0 = (size_t)mblk * 131072;
    const size_t bbase0 = (size_t)head * 65536;

    for (int kb = 0; kb < 16; ++kb) {
        __syncthreads();
        {
            const size_t ab = abase0 + (size_t)kb * 8192;
            const size_t bb = bbase0 + (size_t)kb * 4096;
#pragma unroll
            for (int j = 0; j < 4; ++j) {
                int seg = j * 256 + tid;
                gl_lds16(Xh + ab + seg * 8, &lds[seg * 8]);
                gl_lds16(Xl + ab + seg * 8, &lds[8192 + seg * 8]);
            }
#pragma unroll
            for (int j = 0; j < 2; ++j) {
                int seg = j * 256 + tid;
                gl_lds16(Wqh + bb + seg * 8, &lds[16384 + seg * 8]);
                gl_lds16(Wql + bb + seg * 8, &lds[20480 + seg * 8]);
                gl_lds16(Wkh + bb + seg * 8, &lds[24576 + seg * 8]);
                gl_lds16(Wkl + bb + seg * 8, &lds[28672 + seg * 8]);
                gl_lds16(Wvt + bb + seg * 8, &lds[32768 + seg * 8]);
            }
        }
        __syncthreads();

#pragma unroll
        for (int ksub = 0; ksub < 2; ++ksub) {
            bf16x8 ah[2], al8[2];
#pragma unroll
            for (int mt = 0; mt < 2; ++mt) {
                int row = w * 32 + mt * 16 + l15;
                int g = (ksub * 4 + quad) ^ (row & 7);
                ah[mt] = *(const bf16x8*)&lds[row * 64 + g * 8];
                al8[mt] = *(const bf16x8*)&lds[8192 + row * 64 + g * 8];
            }
#pragma unroll
            for (int nt = 0; nt < 4; ++nt) {
                int col = nt * 16 + l15;
                int o = col * 64 + ((ksub * 4 + quad) ^ (col & 7)) * 8;
                bf16x8 bqh = *(const bf16x8*)&lds[16384 + o];
                bf16x8 bql = *(const bf16x8*)&lds[20480 + o];
                bf16x8 bkh = *(const bf16x8*)&lds[24576 + o];
                bf16x8 bkl = *(const bf16x8*)&lds[28672 + o];
                bf16x8 bv = *(const bf16x8*)&lds[32768 + o];
#pragma unroll
                for (int mt = 0; mt < 2; ++mt) {
                    f32x4 a = aq[mt][nt];
                    a = MFMA(ah[mt], bqh, a);
                    a = MFMA(ah[mt], bql, a);
                    a = MFMA(al8[mt], bqh, a);
                    aq[mt][nt] = a;
                    f32x4 b = ak[mt][nt];
                    b = MFMA(ah[mt], bkh, b);
                    b = MFMA(ah[mt], bkl, b);
                    b = MFMA(al8[mt], bkh, b);
                    ak[mt][nt] = b;
                    av[mt][nt] = MFMA(ah[mt], bv, av[mt][nt]);
                }
            }
        }
    }

#pragma unroll
    for (int mt = 0; mt < 2; ++mt) {
        const int rbase = mblk * 128 + w * 32 + mt * 16 + quad * 4;
#pragma unroll
        for (int nt = 0; nt < 4; ++nt) {
            const int col = head * 64 + nt * 16 + l15;
#pragma unroll
            for (int r = 0; r < 4; ++r) {
                size_t a = (size_t)(rbase + r) * D_DIM + col;
                float vq = aq[mt][nt][r];
                unsigned short hq = f2bf(vq);
                Qh[a] = hq;
                Ql[a] = f2bf(vq - bf2f(hq));
                float vk = ak[mt][nt][r];
                unsigned short hk = f2bf(vk);
                Kh[a] = hk;
                Kl[a] = f2bf(vk - bf2f(hk));
            }
            ushort4 vp;
            vp.x = f2bf(av[mt][nt][0]);
            vp.y = f2bf(av[mt][nt][1]);
            vp.z = f2bf(av[mt][nt][2]);
            vp.w = f2bf(av[mt][nt][3]);
            *(ushort4*)(Vt + (size_t)col * (2 * S_LEN) + rbase) = vp;
        }
    }
}

// ---------------------------------------------------------------------------
// attn: flash attention per (dir, head).  Block = 64 q-rows (4 waves x 16),
// key chunks of 64 staged into LDS via global_load_lds (Khi/Klo/V, 24 KB),
// XOR-swizzled on the global-gather side to avoid stride-128B bank conflicts.
// P transposed through per-wave LDS (stride 72, 16B-aligned).
// Output stored with the torch-.view scramble: row q' = h*128 + (q>>4),
// col f = (q&15)*64 + e.
// grid: dir(2) x head(16) x qblk(32) = 1024 blocks
// ---------------------------------------------------------------------------
__global__ __launch_bounds__(256) void attn_kernel(const unsigned short* __restrict__ Qh_,
                                                   const unsigned short* __restrict__ Ql_,
                                                   const unsigned short* __restrict__ Kh_,
                                                   const unsigned short* __restrict__ Kl_,
                                                   const unsigned short* __restrict__ Vt_,
                                                   unsigned short* __restrict__ Oatt) {
    __shared__ unsigned short lds[16896];  // Khi[0,4096) Klo[4096,8192) V[8192,12288) P[12288,16896)
    const int bid = blockIdx.x;
    const int qblk = bid & 31;
    const int head = (bid >> 5) & 15;
    const int dir = bid >> 9;
    const int src_q = dir, src_kv = 1 - dir;

    const int tid = threadIdx.x;
    const int lane = tid & 63;
    const int w = tid >> 6;
    const int l15 = lane & 15, quad = lane >> 4;
    const int q0 = qblk * 64 + w * 16;

    // Q fragments (A-layout): A[m=l15][k=c*32+quad*8+j]
    const size_t qrow = (size_t)(src_q * S_LEN + q0 + l15) * D_DIM + head * 64 + quad * 8;
    bf16x8 qh[2], ql[2];
#pragma unroll
    for (int c = 0; c < 2; ++c) {
        qh[c] = *(const bf16x8*)(Qh_ + qrow + c * 32);
        ql[c] = *(const bf16x8*)(Ql_ + qrow + c * 32);
    }

    f32x4 o[4] = {};
    float mi[4], li[4];
#pragma unroll
    for (int r = 0; r < 4; ++r) {
        mi[r] = -1e30f;
        li[r] = 0.f;
    }

    unsigned short* Pw = lds + 12288 + w * 1152;

    for (int k0 = 0; k0 < S_LEN; k0 += 64) {
        __syncthreads();
        {
            const unsigned short* KhB = Kh_ + (size_t)(src_kv * S_LEN + k0) * D_DIM + head * 64;
            const unsigned short* KlB = Kl_ + (size_t)(src_kv * S_LEN + k0) * D_DIM + head * 64;
            const unsigned short* VB = Vt_ + (size_t)(head * 64) * (2 * S_LEN) + src_kv * S_LEN + k0;
#pragma unroll
            for (int j = 0; j < 2; ++j) {
                int i = j * 256 + tid;  // segment 0..511
                int row = i >> 3, c16 = i & 7;
                int sc = c16 ^ (row & 7);  // swizzle on global side
                gl_lds16(KhB + (size_t)row * D_DIM + sc * 8, &lds[i * 8]);
                gl_lds16(KlB + (size_t)row * D_DIM + sc * 8, &lds[4096 + i * 8]);
                gl_lds16(VB + (size_t)row * (2 * S_LEN) + sc * 8, &lds[8192 + i * 8]);
            }
        }
        __syncthreads();

        // QK^T (split-bf16 3-pass)
        f32x4 sa[4] = {};
#pragma unroll
        for (int nt = 0; nt < 4; ++nt) {
            const int row = nt * 16 + l15;
            const int s0 = (quad ^ (row & 7)) * 8;
            const int s1 = ((4 + quad) ^ (row & 7)) * 8;
            bf16x8 bh0 = *(const bf16x8*)&lds[row * 64 + s0];
            bf16x8 bh1 = *(const bf16x8*)&lds[row * 64 + s1];
            bf16x8 bl0 = *(const bf16x8*)&lds[4096 + row * 64 + s0];
            bf16x8 bl1 = *(const bf16x8*)&lds[4096 + row * 64 + s1];
            f32x4 a = sa[nt];
            a = MFMA(qh[0], bh0, a);
            a = MFMA(qh[1], bh1, a);
            a = MFMA(qh[0], bl0, a);
            a = MFMA(qh[1], bl1, a);
            a = MFMA(ql[0], bh0, a);
            a = MFMA(ql[1], bh1, a);
            sa[nt] = a;
        }

        // online softmax (rows quad*4+r; reduce across l15 within quad)
        float tm[4];
#pragma unroll
        for (int r = 0; r < 4; ++r)
            tm[r] = fmaxf(fmaxf(sa[0][r], sa[1][r]), fmaxf(sa[2][r], sa[3][r]));
#pragma unroll
        for (int off = 1; off <= 8; off <<= 1)
#pragma unroll
            for (int r = 0; r < 4; ++r) tm[r] = fmaxf(tm[r], __shfl_xor(tm[r], off, 64));
        float al[4], rs[4];
#pragma unroll
        for (int r = 0; r < 4; ++r) {
            float mn = fmaxf(mi[r], tm[r]);
            al[r] = __expf(mi[r] - mn);
            mi[r] = mn;
            rs[r] = 0.f;
        }
#pragma unroll
        for (int nt = 0; nt < 4; ++nt)
#pragma unroll
            for (int r = 0; r < 4; ++r) {
                float p = __expf(sa[nt][r] - mi[r]);
                sa[nt][r] = p;
                rs[r] += p;
            }
#pragma unroll
        for (int off = 1; off <= 8; off <<= 1)
#pragma unroll
            for (int r = 0; r < 4; ++r) rs[r] += __shfl_xor(rs[r], off, 64);
#pragma unroll
        for (int r = 0; r < 4; ++r) li[r] = li[r] * al[r] + rs[r];
#pragma unroll
        for (int nt = 0; nt < 4; ++nt)
#pragma unroll
            for (int r = 0; r < 4; ++r) o[nt][r] *= al[r];
#pragma unroll
        for (int nt = 0; nt < 4; ++nt)
#pragma unroll
            for (int r = 0; r < 4; ++r)
                Pw[(quad * 4 + r) * 72 + nt * 16 + l15] = f2bf(sa[nt][r]);

        // PV: A-frags from P LDS, V B-frags from staged LDS
#pragma unroll
        for (int c = 0; c < 2; ++c) {
            bf16x8 af = *(const bf16x8*)(Pw + l15 * 72 + c * 32 + quad * 8);
#pragma unroll
            for (int nt = 0; nt < 4; ++nt) {
                const int row = nt * 16 + l15;
                const int sl = ((c * 4 + quad) ^ (row & 7)) * 8;
                bf16x8 vf = *(const bf16x8*)&lds[8192 + row * 64 + sl];
                o[nt] = MFMA(af, vf, o[nt]);
            }
        }
    }
    // normalize + store with the raw-.view scramble
#pragma unroll
    for (int nt = 0; nt < 4; ++nt)
#pragma unroll
        for (int r = 0; r < 4; ++r) {
            int q = q0 + quad * 4 + r;
            int e = nt * 16 + l15;
            int qp = head * 128 + (q >> 4);
            int f = (q & 15) * 64 + e;
            Oatt[(size_t)(dir * S_LEN + qp) * D_DIM + f] = f2bf(o[nt][r] / li[r]);
        }
}

// ---------------------------------------------------------------------------
// oproj: out[dir] = Oatt[dir] @ Wo   (bf16 MFMA, fp32 out)
// grid: dir(2) x sblk(32) x nblk(16) = 1024 blocks
// ---------------------------------------------------------------------------
__global__ __launch_bounds__(256) void oproj(const unsigned short* __restrict__ Oatt,
                                             const unsigned short* __restrict__ Wot,
                                             float* __restrict__ out) {
    const int bid = blockIdx.x;
    const int nblk = bid & 15;
    const int sblk = (bid >> 4) & 31;
    const int dir = bid >> 9;
    const int lane = threadIdx.x & 63;
    const int w = threadIdx.x >> 6;
    const int l15 = lane & 15, quad = lane >> 4;

    const unsigned short* Ap =
        Oatt + (size_t)(dir * S_LEN + sblk * 64 + w * 16 + l15) * D_DIM + quad * 8;
    const unsigned short* Bp = Wot + (size_t)(nblk * 64 + l15) * D_DIM + quad * 8;

    f32x4 acc[4] = {};
#pragma unroll 2
    for (int kk = 0; kk < D_DIM; kk += 32) {
        bf16x8 a = *(const bf16x8*)(Ap + kk);
#pragma unroll
        for (int nt = 0; nt < 4; ++nt) {
            bf16x8 b = *(const bf16x8*)(Bp + nt * 16384 + kk);
            acc[nt] = MFMA(a, b, acc[nt]);
        }
    }
    const int row = sblk * 64 + w * 16 + quad * 4;
#pragma unroll
    for (int nt = 0; nt < 4; ++nt)
#pragma unroll
        for (int r = 0; r < 4; ++r)
            out[(size_t)dir * (S_LEN * D_DIM) + (size_t)(row + r) * D_DIM + nblk * 64 + nt * 16 +
                l15] = acc[nt][r];
}

// ---------------------------------------------------------------------------
extern "C" void kernel_launch(void* const* d_in, const int* in_sizes, int n_in, void* d_out,
                              int out_size, void* d_ws, size_t ws_size, hipStream_t stream) {
    const float* GLO = (const float*)d_in[0];
    const float* LOC = (const float*)d_in[1];
    const float* Wq = (const float*)d_in[2];
    const float* Wk = (const float*)d_in[3];
    const float* Wv = (const float*)d_in[4];
    const float* Wo = (const float*)d_in[5];
    float* out = (float*)d_out;

    // workspace layout (ushort element offsets); total 79,691,776 bytes
    unsigned short* ws = (unsigned short*)d_ws;
    unsigned short* Xh = ws + 0;
    unsigned short* Xl = ws + 4194304;
    unsigned short* Wqh = ws + 8388608;
    unsigned short* Wql = ws + 9437184;
    unsigned short* Wkh = ws + 10485760;
    unsigned short* Wkl = ws + 11534336;
    unsigned short* Wvt = ws + 12582912;
    unsigned short* Wot = ws + 13631488;
    unsigned short* Qh = ws + 14680064;
    unsigned short* Ql = ws + 18874368;
    unsigned short* Kh = ws + 23068672;
    unsigned short* Kl = ws + 27262976;
    unsigned short* Vt = ws + 31457280;
    unsigned short* Oatt = ws + 35651584;

    prep<<<32768, 256, 0, stream>>>(GLO, LOC, Wq, Wk, Wv, Wo, Xh, Xl, Wqh, Wql, Wkh, Wkl, Wvt, Wot);
    qkv_proj<<<512, 256, 0, stream>>>(Xh, Xl, Wqh, Wql, Wkh, Wkl, Wvt, Qh, Ql, Kh, Kl, Vt);
    attn_kernel<<<1024, 256, 0, stream>>>(Qh, Ql, Kh, Kl, Vt, Oatt);
    oproj<<<1024, 256, 0, stream>>>(Oatt, Wot, out);
}

// Round 4
// 291.351 us; speedup vs baseline: 2.4967x; 1.1935x over previous
//
#include <hip/hip_runtime.h>
#include <math.h>

#define S_LEN 2048
#define D_DIM 1024
#define NH 16
#define HD 64

typedef __attribute__((ext_vector_type(8))) short bf16x8;
typedef __attribute__((ext_vector_type(4))) float f32x4;

#define MFMA(a, b, c) __builtin_amdgcn_mfma_f32_16x16x32_bf16((a), (b), (c), 0, 0, 0)

__device__ __forceinline__ unsigned short f2bf(float x) {
    unsigned int u = __float_as_uint(x);
    u = (u + 0x7FFFu + ((u >> 16) & 1u)) >> 16;  // round-to-nearest-even
    return (unsigned short)u;
}
__device__ __forceinline__ float bf2f(unsigned short b) {
    return __uint_as_float(((unsigned int)b) << 16);
}
__device__ __forceinline__ void gl_lds16(const void* g, void* l) {
    __builtin_amdgcn_global_load_lds((const __attribute__((address_space(1))) unsigned int*)g,
                                     (__attribute__((address_space(3))) unsigned int*)l, 16, 0, 0);
}

// Tiled-swizzled layouts (identity-copy global_load_lds staging, 2-way LDS reads):
//   X/Oatt : [mblk=r>>7][kblk=k>>6][row=r&127][g=((k>>3)&7)^(r&7)][k&7]
//   Wqkv   : [head][kblk=d>>6][col=e][g=((d>>3)&7)^(e&7)][d&7]
//   Wo     : [nblk=n>>6][kblk=k>>6][col=n&63][g=((k>>3)&7)^(n&7)][k&7]

// ---------------------------------------------------------------------------
// prep: input split + weight transpose/split (coalesced reads, scatter writes)
// Wq folded scale = 0.125 * log2(e)  -> scores live in exp2 domain.
// ---------------------------------------------------------------------------
__global__ __launch_bounds__(256) void prep(const float* __restrict__ GLO,
                                            const float* __restrict__ LOC,
                                            const float* __restrict__ Wq,
                                            const float* __restrict__ Wk,
                                            const float* __restrict__ Wv,
                                            const float* __restrict__ Wo,
                                            unsigned short* __restrict__ Xh,
                                            unsigned short* __restrict__ Xl,
                                            unsigned short* __restrict__ Wqh,
                                            unsigned short* __restrict__ Wql,
                                            unsigned short* __restrict__ Wkh,
                                            unsigned short* __restrict__ Wkl,
                                            unsigned short* __restrict__ Wvt,
                                            unsigned short* __restrict__ Wot) {
    int idx = blockIdx.x * 256 + threadIdx.x;  // 0 .. 8M-1
    if (idx < (1 << 22)) {
        const float* src = (idx & (1 << 21)) ? LOC : GLO;
        float x = src[idx & ((1 << 21) - 1)];
        int r = idx >> 10;  // 0..4095
        int k = idx & 1023;
        size_t t = (size_t)(r >> 7) * 131072 + (size_t)(k >> 6) * 8192 + (r & 127) * 64 +
                   ((((k >> 3) & 7) ^ (r & 7)) * 8) + (k & 7);
        unsigned short h = f2bf(x);
        Xh[t] = h;
        Xl[t] = f2bf(x - bf2f(h));
    } else {
        idx -= (1 << 22);
        int sec = idx >> 20;
        int i = idx & 0xFFFFF;
        if (sec < 3) {
            int e = i & 63;             // fastest -> coalesced read
            int d = (i >> 6) & 1023;
            int h = i >> 16;
            float wv = ((sec == 0) ? Wq : (sec == 1) ? Wk : Wv)[h * 65536 + d * 64 + e];
            size_t t = (size_t)h * 65536 + (size_t)(d >> 6) * 4096 + e * 64 +
                       ((((d >> 3) & 7) ^ (e & 7)) * 8) + (d & 7);
            if (sec == 0) {
                wv *= 0.18033688011112042f;  // 0.125 * log2(e)
                unsigned short hi = f2bf(wv);
                Wqh[t] = hi;
                Wql[t] = f2bf(wv - bf2f(hi));
            } else if (sec == 1) {
                unsigned short hi = f2bf(wv);
                Wkh[t] = hi;
                Wkl[t] = f2bf(wv - bf2f(hi));
            } else {
                Wvt[t] = f2bf(wv);
            }
        } else {
            int n = i & 1023;  // fastest -> coalesced read of Wo[k*1024+n]
            int k = i >> 10;
            size_t t = (size_t)(n >> 6) * 65536 + (size_t)(k >> 6) * 4096 + (n & 63) * 64 +
                       ((((k >> 3) & 7) ^ (n & 7)) * 8) + (k & 7);
            Wot[t] = f2bf(Wo[k * 1024 + n]);
        }
    }
}

// ---------------------------------------------------------------------------
// qkv_proj: staged-LDS GEMM, 7 MFMA passes share staged A/B.
// grid: mblk(32) x head(16) = 512 blocks
// ---------------------------------------------------------------------------
__global__ __launch_bounds__(256) void qkv_proj(const unsigned short* __restrict__ Xh,
                                                const unsigned short* __restrict__ Xl,
                                                const unsigned short* __restrict__ Wqh,
                                                const unsigned short* __restrict__ Wql,
                                                const unsigned short* __restrict__ Wkh,
                                                const unsigned short* __restrict__ Wkl,
                                                const unsigned short* __restrict__ Wvt,
                                                unsigned short* __restrict__ Qh,
                                                unsigned short* __restrict__ Ql,
                                                unsigned short* __restrict__ Kh,
                                                unsigned short* __restrict__ Kl,
                                                unsigned short* __restrict__ Vt) {
    __shared__ unsigned short lds[36864];
    const int bid = blockIdx.x;
    const int mblk = bid & 31;
    const int head = bid >> 5;
    const int tid = threadIdx.x;
    const int lane = tid & 63;
    const int w = tid >> 6;
    const int l15 = lane & 15, quad = lane >> 4;

    f32x4 aq[2][4] = {}, ak[2][4] = {}, av[2][4] = {};
    const size_t abase0 = (size_t)mblk * 131072;
    const size_t bbase0 = (size_t)head * 65536;

    for (int kb = 0; kb < 16; ++kb) {
        __syncthreads();
        {
            const size_t ab = abase0 + (size_t)kb * 8192;
            const size_t bb = bbase0 + (size_t)kb * 4096;
#pragma unroll
            for (int j = 0; j < 4; ++j) {
                int seg = j * 256 + tid;
                gl_lds16(Xh + ab + seg * 8, &lds[seg * 8]);
                gl_lds16(Xl + ab + seg * 8, &lds[8192 + seg * 8]);
            }
#pragma unroll
            for (int j = 0; j < 2; ++j) {
                int seg = j * 256 + tid;
                gl_lds16(Wqh + bb + seg * 8, &lds[16384 + seg * 8]);
                gl_lds16(Wql + bb + seg * 8, &lds[20480 + seg * 8]);
                gl_lds16(Wkh + bb + seg * 8, &lds[24576 + seg * 8]);
                gl_lds16(Wkl + bb + seg * 8, &lds[28672 + seg * 8]);
                gl_lds16(Wvt + bb + seg * 8, &lds[32768 + seg * 8]);
            }
        }
        __syncthreads();

#pragma unroll
        for (int ksub = 0; ksub < 2; ++ksub) {
            bf16x8 ah[2], al8[2];
#pragma unroll
            for (int mt = 0; mt < 2; ++mt) {
                int row = w * 32 + mt * 16 + l15;
                int g = (ksub * 4 + quad) ^ (row & 7);
                ah[mt] = *(const bf16x8*)&lds[row * 64 + g * 8];
                al8[mt] = *(const bf16x8*)&lds[8192 + row * 64 + g * 8];
            }
#pragma unroll
            for (int nt = 0; nt < 4; ++nt) {
                int col = nt * 16 + l15;
                int o = col * 64 + ((ksub * 4 + quad) ^ (col & 7)) * 8;
                bf16x8 bqh = *(const bf16x8*)&lds[16384 + o];
                bf16x8 bql = *(const bf16x8*)&lds[20480 + o];
                bf16x8 bkh = *(const bf16x8*)&lds[24576 + o];
                bf16x8 bkl = *(const bf16x8*)&lds[28672 + o];
                bf16x8 bv = *(const bf16x8*)&lds[32768 + o];
#pragma unroll
                for (int mt = 0; mt < 2; ++mt) {
                    f32x4 a = aq[mt][nt];
                    a = MFMA(ah[mt], bqh, a);
                    a = MFMA(ah[mt], bql, a);
                    a = MFMA(al8[mt], bqh, a);
                    aq[mt][nt] = a;
                    f32x4 b = ak[mt][nt];
                    b = MFMA(ah[mt], bkh, b);
                    b = MFMA(ah[mt], bkl, b);
                    b = MFMA(al8[mt], bkh, b);
                    ak[mt][nt] = b;
                    av[mt][nt] = MFMA(ah[mt], bv, av[mt][nt]);
                }
            }
        }
    }

#pragma unroll
    for (int mt = 0; mt < 2; ++mt) {
        const int rbase = mblk * 128 + w * 32 + mt * 16 + quad * 4;
#pragma unroll
        for (int nt = 0; nt < 4; ++nt) {
            const int col = head * 64 + nt * 16 + l15;
#pragma unroll
            for (int r = 0; r < 4; ++r) {
                size_t a = (size_t)(rbase + r) * D_DIM + col;
                float vq = aq[mt][nt][r];
                unsigned short hq = f2bf(vq);
                Qh[a] = hq;
                Ql[a] = f2bf(vq - bf2f(hq));
                float vk = ak[mt][nt][r];
                unsigned short hk = f2bf(vk);
                Kh[a] = hk;
                Kl[a] = f2bf(vk - bf2f(hk));
            }
            ushort4 vp;
            vp.x = f2bf(av[mt][nt][0]);
            vp.y = f2bf(av[mt][nt][1]);
            vp.z = f2bf(av[mt][nt][2]);
            vp.w = f2bf(av[mt][nt][3]);
            *(ushort4*)(Vt + (size_t)col * (2 * S_LEN) + rbase) = vp;
        }
    }
}

// ---------------------------------------------------------------------------
// attn: flash attention, S^T = K.Q^T formulation.  Block = 128 q-rows
// (4 waves x 32), key chunks of 64 staged in LDS (Khi/Klo/V, 24 KB, swizzled).
// Per-lane: q = l15 (per-lane scalar softmax state), keys = quad*4+r.
// P^T kept per-wave in LDS [q][key] (stride 72) -> b64 packed writes,
// b128 B-frag reads for PV (out^T = V^T . P^T).
// Output stored into the TILED Oatt layout (feeds staged oproj).
// grid: dir(2) x head(16) x qblk(16) = 512 blocks
// ---------------------------------------------------------------------------
__global__ __launch_bounds__(256) void attn_kernel(const unsigned short* __restrict__ Qh_,
                                                   const unsigned short* __restrict__ Ql_,
                                                   const unsigned short* __restrict__ Kh_,
                                                   const unsigned short* __restrict__ Kl_,
                                                   const unsigned short* __restrict__ Vt_,
                                                   unsigned short* __restrict__ Oatt) {
    __shared__ unsigned short lds[21504];  // Khi 4096, Klo 4096, V 4096, P 4x2304
    const int bid = blockIdx.x;
    const int qblk = bid & 15;
    const int head = (bid >> 4) & 15;
    const int dir = bid >> 8;
    const int src_q = dir, src_kv = 1 - dir;

    const int tid = threadIdx.x;
    const int lane = tid & 63;
    const int w = tid >> 6;
    const int l15 = lane & 15, quad = lane >> 4;
    const int q0w = qblk * 128 + w * 32;

    // Q fragments (B-operand): B[k=e][n=q], lane n=l15, k=quad*8+j (+c*32)
    bf16x8 qh[2][2], ql[2][2];
#pragma unroll
    for (int mt = 0; mt < 2; ++mt) {
        const size_t qrow =
            (size_t)(src_q * S_LEN + q0w + mt * 16 + l15) * D_DIM + head * 64 + quad * 8;
#pragma unroll
        for (int c = 0; c < 2; ++c) {
            qh[mt][c] = *(const bf16x8*)(Qh_ + qrow + c * 32);
            ql[mt][c] = *(const bf16x8*)(Ql_ + qrow + c * 32);
        }
    }

    f32x4 o[2][4] = {};  // out^T tiles: [mt(q-tile)][et(e-tile)], lane: q=l15, e=quad*4+r
    float mi[2] = {-1e30f, -1e30f}, li[2] = {0.f, 0.f};
    unsigned short* Pw = lds + 12288 + w * 2304;

    for (int k0 = 0; k0 < S_LEN; k0 += 64) {
        __syncthreads();
        {
            const unsigned short* KhB = Kh_ + (size_t)(src_kv * S_LEN + k0) * D_DIM + head * 64;
            const unsigned short* KlB = Kl_ + (size_t)(src_kv * S_LEN + k0) * D_DIM + head * 64;
            const unsigned short* VB = Vt_ + (size_t)(head * 64) * (2 * S_LEN) + src_kv * S_LEN + k0;
#pragma unroll
            for (int j = 0; j < 2; ++j) {
                int i = j * 256 + tid;  // 0..511
                int row = i >> 3, c16 = i & 7;
                int sc = c16 ^ (row & 7);
                gl_lds16(KhB + (size_t)row * D_DIM + sc * 8, &lds[i * 8]);
                gl_lds16(KlB + (size_t)row * D_DIM + sc * 8, &lds[4096 + i * 8]);
                gl_lds16(VB + (size_t)row * (2 * S_LEN) + sc * 8, &lds[8192 + i * 8]);
            }
        }
        __syncthreads();

        // S^T tiles: sa[mt][kt], keys kt*16+quad*4+r, q = l15 (3-pass split-bf16)
        f32x4 sa[2][4];
#pragma unroll
        for (int kt = 0; kt < 4; ++kt) {
            const int row = kt * 16 + l15;
            const int s0 = (quad ^ (row & 7)) * 8;
            const int s1 = ((4 + quad) ^ (row & 7)) * 8;
            bf16x8 kh0 = *(const bf16x8*)&lds[row * 64 + s0];
            bf16x8 kh1 = *(const bf16x8*)&lds[row * 64 + s1];
            bf16x8 kl0 = *(const bf16x8*)&lds[4096 + row * 64 + s0];
            bf16x8 kl1 = *(const bf16x8*)&lds[4096 + row * 64 + s1];
#pragma unroll
            for (int mt = 0; mt < 2; ++mt) {
                f32x4 a = {};
                a = MFMA(kh0, qh[mt][0], a);
                a = MFMA(kh1, qh[mt][1], a);
                a = MFMA(kl0, qh[mt][0], a);
                a = MFMA(kl1, qh[mt][1], a);
                a = MFMA(kh0, ql[mt][0], a);
                a = MFMA(kh1, ql[mt][1], a);
                sa[mt][kt] = a;
            }
        }

        // online softmax in exp2 domain; per-lane scalar state (q = l15)
#pragma unroll
        for (int mt = 0; mt < 2; ++mt) {
            f32x4 t4 = __builtin_elementwise_max(__builtin_elementwise_max(sa[mt][0], sa[mt][1]),
                                                 __builtin_elementwise_max(sa[mt][2], sa[mt][3]));
            float tm = fmaxf(fmaxf(t4[0], t4[1]), fmaxf(t4[2], t4[3]));
            tm = fmaxf(tm, __shfl_xor(tm, 16, 64));
            tm = fmaxf(tm, __shfl_xor(tm, 32, 64));
            float mn = fmaxf(mi[mt], tm);
            float al = exp2f(mi[mt] - mn);
            mi[mt] = mn;
            const f32x4 mnv = {mn, mn, mn, mn};
            f32x4 rs4 = {};
#pragma unroll
            for (int kt = 0; kt < 4; ++kt) {
                f32x4 p = sa[mt][kt] - mnv;
#pragma unroll
                for (int r = 0; r < 4; ++r) p[r] = exp2f(p[r]);
                rs4 += p;
                unsigned u0 = __float_as_uint(p[0]) + 0x8000u;
                unsigned u1 = __float_as_uint(p[1]) + 0x8000u;
                unsigned u2 = __float_as_uint(p[2]) + 0x8000u;
                unsigned u3 = __float_as_uint(p[3]) + 0x8000u;
                uint2 pk;
                pk.x = __builtin_amdgcn_perm(u1, u0, 0x07060302u);
                pk.y = __builtin_amdgcn_perm(u3, u2, 0x07060302u);
                *(uint2*)&Pw[(mt * 16 + l15) * 72 + kt * 16 + quad * 4] = pk;
            }
            float rs = (rs4[0] + rs4[1]) + (rs4[2] + rs4[3]);
            rs += __shfl_xor(rs, 16, 64);
            rs += __shfl_xor(rs, 32, 64);
            li[mt] = li[mt] * al + rs;
            const f32x4 alv = {al, al, al, al};
#pragma unroll
            for (int et = 0; et < 4; ++et) o[mt][et] *= alv;
        }

        // PV: out^T = V^T . P^T  (A = staged V [e][key], B = P^T [q][key])
#pragma unroll
        for (int c = 0; c < 2; ++c) {
            bf16x8 pf[2];
#pragma unroll
            for (int mt = 0; mt < 2; ++mt)
                pf[mt] = *(const bf16x8*)&Pw[(mt * 16 + l15) * 72 + c * 32 + quad * 8];
#pragma unroll
            for (int et = 0; et < 4; ++et) {
                const int row = et * 16 + l15;
                const int sl = ((c * 4 + quad) ^ (row & 7)) * 8;
                bf16x8 vf = *(const bf16x8*)&lds[8192 + row * 64 + sl];
#pragma unroll
                for (int mt = 0; mt < 2; ++mt) o[mt][et] = MFMA(vf, pf[mt], o[mt][et]);
            }
        }
    }

    // epilogue: normalize, store to TILED Oatt (r_view = dir*2048+head*128+(q>>4),
    // c = (q&15)*64+e; q&15 == l15 here)
    const size_t obase = (size_t)(dir * 16 + head) * 131072 + (size_t)l15 * 8192;
#pragma unroll
    for (int mt = 0; mt < 2; ++mt) {
        float rl = __builtin_amdgcn_rcpf(li[mt]);
        const int rowit = qblk * 8 + w * 2 + mt;
#pragma unroll
        for (int et = 0; et < 4; ++et) {
            int g = ((et * 2 + (quad >> 1)) ^ (rowit & 7)) & 7;
            ushort4 pk;
            pk.x = f2bf(o[mt][et][0] * rl);
            pk.y = f2bf(o[mt][et][1] * rl);
            pk.z = f2bf(o[mt][et][2] * rl);
            pk.w = f2bf(o[mt][et][3] * rl);
            *(ushort4*)(Oatt + obase + (size_t)rowit * 64 + g * 8 + (quad & 1) * 4) = pk;
        }
    }
}

// ---------------------------------------------------------------------------
// oproj: out = view @ Wo, staged-LDS GEMM over tiled Oatt / tiled Wot.
// grid: mblk(32) x nblk(16) = 512 blocks
// ---------------------------------------------------------------------------
__global__ __launch_bounds__(256) void oproj(const unsigned short* __restrict__ Oatt,
                                             const unsigned short* __restrict__ Wot,
                                             float* __restrict__ out) {
    __shared__ unsigned short lds[12288];  // A 8192, B 4096
    const int bid = blockIdx.x;
    const int nblk = bid & 15;
    const int mblk = bid >> 4;
    const int tid = threadIdx.x;
    const int lane = tid & 63, w = tid >> 6, l15 = lane & 15, quad = lane >> 4;

    f32x4 acc[2][4] = {};
    const size_t abase = (size_t)mblk * 131072;
    const size_t bbase = (size_t)nblk * 65536;
    for (int kb = 0; kb < 16; ++kb) {
        __syncthreads();
#pragma unroll
        for (int j = 0; j < 4; ++j) {
            int seg = j * 256 + tid;
            gl_lds16(Oatt + abase + (size_t)kb * 8192 + seg * 8, &lds[seg * 8]);
        }
#pragma unroll
        for (int j = 0; j < 2; ++j) {
            int seg = j * 256 + tid;
            gl_lds16(Wot + bbase + (size_t)kb * 4096 + seg * 8, &lds[8192 + seg * 8]);
        }
        __syncthreads();
#pragma unroll
        for (int ksub = 0; ksub < 2; ++ksub) {
            bf16x8 a[2];
#pragma unroll
            for (int mt = 0; mt < 2; ++mt) {
                int row = w * 32 + mt * 16 + l15;
                a[mt] = *(const bf16x8*)&lds[row * 64 + (((ksub * 4 + quad) ^ (row & 7)) * 8)];
            }
#pragma unroll
            for (int nt = 0; nt < 4; ++nt) {
                int col = nt * 16 + l15;
                bf16x8 b =
                    *(const bf16x8*)&lds[8192 + col * 64 + (((ksub * 4 + quad) ^ (col & 7)) * 8)];
#pragma unroll
                for (int mt = 0; mt < 2; ++mt) acc[mt][nt] = MFMA(a[mt], b, acc[mt][nt]);
            }
        }
    }
#pragma unroll
    for (int mt = 0; mt < 2; ++mt) {
        const int rbase = mblk * 128 + w * 32 + mt * 16 + quad * 4;
#pragma unroll
        for (int nt = 0; nt < 4; ++nt)
#pragma unroll
            for (int r = 0; r < 4; ++r)
                out[(size_t)(rbase + r) * D_DIM + nblk * 64 + nt * 16 + l15] = acc[mt][nt][r];
    }
}

// ---------------------------------------------------------------------------
extern "C" void kernel_launch(void* const* d_in, const int* in_sizes, int n_in, void* d_out,
                              int out_size, void* d_ws, size_t ws_size, hipStream_t stream) {
    const float* GLO = (const float*)d_in[0];
    const float* LOC = (const float*)d_in[1];
    const float* Wq = (const float*)d_in[2];
    const float* Wk = (const float*)d_in[3];
    const float* Wv = (const float*)d_in[4];
    const float* Wo = (const float*)d_in[5];
    float* out = (float*)d_out;

    unsigned short* ws = (unsigned short*)d_ws;
    unsigned short* Xh = ws + 0;
    unsigned short* Xl = ws + 4194304;
    unsigned short* Wqh = ws + 8388608;
    unsigned short* Wql = ws + 9437184;
    unsigned short* Wkh = ws + 10485760;
    unsigned short* Wkl = ws + 11534336;
    unsigned short* Wvt = ws + 12582912;
    unsigned short* Wot = ws + 13631488;
    unsigned short* Qh = ws + 14680064;
    unsigned short* Ql = ws + 18874368;
    unsigned short* Kh = ws + 23068672;
    unsigned short* Kl = ws + 27262976;
    unsigned short* Vt = ws + 31457280;
    unsigned short* Oatt = ws + 35651584;

    prep<<<32768, 256, 0, stream>>>(GLO, LOC, Wq, Wk, Wv, Wo, Xh, Xl, Wqh, Wql, Wkh, Wkl, Wvt, Wot);
    qkv_proj<<<512, 256, 0, stream>>>(Xh, Xl, Wqh, Wql, Wkh, Wkl, Wvt, Qh, Ql, Kh, Kl, Vt);
    attn_kernel<<<512, 256, 0, stream>>>(Qh, Ql, Kh, Kl, Vt, Oatt);
    oproj<<<512, 256, 0, stream>>>(Oatt, Wot, out);
}